// Round 19
// baseline (200.651 us; speedup 1.0000x reference)
//
#include <hip/hip_runtime.h>

typedef __attribute__((ext_vector_type(8))) short bf16x8;
typedef __attribute__((ext_vector_type(4))) float f32x4;
typedef __attribute__((ext_vector_type(8))) unsigned short u16x8;
typedef __attribute__((ext_vector_type(2))) unsigned int u32x2;

#define H_Q   16
#define NH    18            // 16 q heads + 1 k + 1 v
#define SEQ   2048
#define BATCH 2
#define HID   2048
#define NQKV  2304          // NH*128
// q scale folded into attn's in-register rope: (1/sqrt(128)) * log2(e)
#define QK_SCALE2 0.1275174313f

#if defined(__has_builtin)
# if __has_builtin(__builtin_amdgcn_exp2f)
#  define EXP2(x) __builtin_amdgcn_exp2f(x)
# endif
#endif
#ifndef EXP2
# define EXP2(x) exp2f(x)
#endif

__device__ __forceinline__ float bf2f(unsigned short u){
  union { unsigned int u; float f; } x; x.u = ((unsigned int)u) << 16; return x.f;
}
__device__ __forceinline__ unsigned short f2bf(float f){
  union { float f; unsigned int u; } x; x.f = f;
  unsigned int r = x.u + 0x7fffu + ((x.u >> 16) & 1u);
  return (unsigned short)(r >> 16);
}
// packed f32x2 -> bf16x2 (RNE, matches f2bf) in ONE VALU instruction
__device__ __forceinline__ unsigned int cvtpk(float lo, float hi){
  unsigned int r;
  asm("v_cvt_pk_bf16_f32 %0, %1, %2" : "=v"(r) : "v"(lo), "v"(hi));
  return r;
}

// ---------------------------------------------------------------- f32 -> bf16 convert
__global__ __launch_bounds__(256) void convert_bf16(const float* __restrict__ src,
                                                    unsigned short* __restrict__ dst){
  const size_t i0 = ((size_t)blockIdx.x * 256 + threadIdx.x) * 16;
  f32x4 a = *(const f32x4*)(src + i0);
  f32x4 b = *(const f32x4*)(src + i0 + 4);
  f32x4 c = *(const f32x4*)(src + i0 + 8);
  f32x4 d = *(const f32x4*)(src + i0 + 12);
  u16x8 lo, hi;
#pragma unroll
  for (int j = 0; j < 4; ++j){
    lo[j] = f2bf(a[j]); lo[4+j] = f2bf(b[j]);
    hi[j] = f2bf(c[j]); hi[4+j] = f2bf(d[j]);
  }
  *(u16x8*)(dst + i0)     = lo;
  *(u16x8*)(dst + i0 + 8) = hi;
}

// ---------------------------------------------------------------- transpose + convert
__global__ __launch_bounds__(256) void transpose_f2b(const float* __restrict__ W,
                                                     unsigned short* __restrict__ WT,
                                                     int K, int N){
  __shared__ float tile[64][72];
  const int t = threadIdx.x;
  const int nt = blockIdx.x * 64, kt = blockIdx.y * 64;
#pragma unroll
  for (int p = 0; p < 2; ++p){
    int slot = p*256 + t, r = slot >> 3, c = (slot & 7) * 8;
    *(f32x4*)&tile[r][c]     = *(const f32x4*)(W + (size_t)(kt + r)*N + nt + c);
    *(f32x4*)&tile[r][c + 4] = *(const f32x4*)(W + (size_t)(kt + r)*N + nt + c + 4);
  }
  __syncthreads();
#pragma unroll
  for (int p = 0; p < 2; ++p){
    int slot = p*256 + t, r = slot >> 3, c = (slot & 7) * 8;
    u16x8 v;
#pragma unroll
    for (int j = 0; j < 8; ++j) v[j] = f2bf(tile[c + j][r]);
    *(u16x8*)(WT + (size_t)(nt + r)*K + kt + c) = v;
  }
}

// ---------------------------------------------------------------- GEMM (B^T input)
template<bool F32OUT>
__global__ __launch_bounds__(256, 2) void gemm_bt(const unsigned short* __restrict__ A,
                                                  const unsigned short* __restrict__ Bt,
                                                  void* __restrict__ Cv,
                                                  int M, int N, int K){
  __shared__ unsigned short lds[2][2][128*32];
  const int tid  = threadIdx.x;
  const int wave = tid >> 6, lane = tid & 63;
  const int row0 = blockIdx.x * 128, col0 = blockIdx.y * 128;
  const int wr = (wave >> 1) * 64, wc = (wave & 1) * 64;
  const int lm = lane & 15, lk = (lane >> 4) * 8;
  f32x4 acc[4][4] = {};

  auto stage = [&](int buf, int kt){
#pragma unroll
    for (int i = 0; i < 2; ++i){
      int slot = i*256 + tid;
      int r = slot >> 2, kc = (slot & 3) * 8;
      const unsigned short* ga = A  + (size_t)(row0 + r)*K + kt*32 + kc;
      const unsigned short* gb = Bt + (size_t)(col0 + r)*K + kt*32 + kc;
      unsigned short* la = &lds[buf][0][(i*256 + (wave << 6)) * 8];
      unsigned short* lb = &lds[buf][1][(i*256 + (wave << 6)) * 8];
      __builtin_amdgcn_global_load_lds((const __attribute__((address_space(1))) void*)ga,
                                       (__attribute__((address_space(3))) void*)la, 16, 0, 0);
      __builtin_amdgcn_global_load_lds((const __attribute__((address_space(1))) void*)gb,
                                       (__attribute__((address_space(3))) void*)lb, 16, 0, 0);
    }
  };

  stage(0, 0);
  const int KT = K >> 5;
  int buf = 0;
  for (int kt = 0; kt < KT; ++kt){
    __syncthreads();
    if (kt + 1 < KT) stage(buf ^ 1, kt + 1);
    const unsigned short* la = lds[buf][0];
    const unsigned short* lb = lds[buf][1];
    bf16x8 af[4], bfr[4];
#pragma unroll
    for (int i = 0; i < 4; ++i) af[i]  = *(const bf16x8*)&la[(wr + i*16 + lm)*32 + lk];
#pragma unroll
    for (int j = 0; j < 4; ++j) bfr[j] = *(const bf16x8*)&lb[(wc + j*16 + lm)*32 + lk];
#pragma unroll
    for (int i = 0; i < 4; ++i)
#pragma unroll
      for (int j = 0; j < 4; ++j)
        acc[i][j] = __builtin_amdgcn_mfma_f32_16x16x32_bf16(af[i], bfr[j], acc[i][j], 0, 0, 0);
    buf ^= 1;
  }

#pragma unroll
  for (int i = 0; i < 4; ++i){
    int row = row0 + wr + i*16 + (lane >> 4) * 4;
#pragma unroll
    for (int j = 0; j < 4; ++j){
      int col = col0 + wc + j*16 + lm;
#pragma unroll
      for (int r = 0; r < 4; ++r){
        if (F32OUT) ((float*)Cv)[(size_t)(row + r)*N + col] = acc[i][j][r];
        else ((unsigned short*)Cv)[(size_t)(row + r)*N + col] = f2bf(acc[i][j][r]);
      }
    }
  }
}

// ---------------------------------------------------------------- RoPE K + transpose V only
// (q rope is fused into attn_fwd; qkv buffer is read-only here)
__global__ __launch_bounds__(128) void rope_kv(const unsigned short* __restrict__ qkv,
                                               const float* __restrict__ cosb,
                                               const float* __restrict__ sinb,
                                               unsigned short* __restrict__ Kb,
                                               unsigned short* __restrict__ Vt){
  const int bs = blockIdx.x;
  const int s = bs & (SEQ-1), b = bs >> 11;
  const int t = threadIdx.x;
  const unsigned short* row = qkv + (size_t)bs * NQKV;
  if (t < 64){
    const float* cr = cosb + (size_t)s * 128;
    const float* sr = sinb + (size_t)s * 128;
    const unsigned short* kk = row + H_Q*128;
    int d = t;
    float c  = cr[d], sn = sr[d];
    float x1 = bf2f(kk[d]), x2 = bf2f(kk[d + 64]);
    unsigned short* ko = Kb + ((size_t)b*SEQ + s)*128;
    ko[d]      = f2bf(x1*c - x2*sn);
    ko[d + 64] = f2bf(x2*c + x1*sn);
  }
  Vt[((size_t)b*128 + t)*SEQ + s] = row[(H_Q + 1)*128 + t];
}

// ---------------------------------------------------------------- attention
// 64-key LDS tiles (2x32-key passes), counted-vmcnt prefetch (2 ahead), native exp2,
// cvt_pk+permlane P path. Q-RoPE + scale fused in-register (lane-local d<->d+64 pairing).
__global__ __launch_bounds__(256, 2) void attn_fwd(const unsigned short* __restrict__ qkv,
                                                   const float* __restrict__ cosb,
                                                   const float* __restrict__ sinb,
                                                   const unsigned short* __restrict__ Kb,
                                                   const unsigned short* __restrict__ Vt,
                                                   unsigned short* __restrict__ Ob){
  __shared__ unsigned short kls[2][64*128];   // [key][d] swizzled chunk16 ^= key&7 (16KB)
  __shared__ unsigned short vls[2][128*64];   // [d][key] swizzled chunk8 ^= d&7 (16KB)
  const int tid = threadIdx.x, lane = tid & 63;
  const int g = lane >> 4, m = lane & 15;
  const int wg = blockIdx.x;                  // 512 blocks, bh-major
  const int bh = wg >> 4, qb = wg & 15;
  const int b = bh >> 4, h = bh & 15;
  const int q0 = qb * 128 + (tid >> 6) * 32;

  // ---- in-register Q RoPE + scale: chunk dc pairs with dc+2 (d <-> d+64), lane-local
  bf16x8 qfA[4], qfB[4];
  auto ropeQ = [&](int qoff, bf16x8* qf){
    const int s = q0 + qoff + m;
    const unsigned short* qr = qkv + ((size_t)((b << 11) + s)*NH + h)*128;
    const float* cp = cosb + (size_t)s * 128;
    const float* sp = sinb + (size_t)s * 128;
    float x[4][8];
#pragma unroll
    for (int dc = 0; dc < 4; ++dc){
      bf16x8 v = *(const bf16x8*)(qr + dc*32 + g*8);
#pragma unroll
      for (int j = 0; j < 8; ++j) x[dc][j] = bf2f((unsigned short)v[j]);
    }
    union { unsigned int w[4]; bf16x8 v; } U[4];
#pragma unroll
    for (int dc = 0; dc < 2; ++dc){
#pragma unroll
      for (int jp = 0; jp < 4; ++jp){
        float rl[2], rh[2];
#pragma unroll
        for (int e = 0; e < 2; ++e){
          int j = 2*jp + e;
          int d = dc*32 + g*8 + j;
          float c1 = cp[d], s1 = sp[d], c2 = cp[d+64], s2 = sp[d+64];
          rl[e] = (x[dc][j]*c1 - x[dc+2][j]*s1) * QK_SCALE2;
          rh[e] = (x[dc+2][j]*c2 + x[dc][j]*s2) * QK_SCALE2;
        }
        U[dc].w[jp]     = cvtpk(rl[0], rl[1]);
        U[dc+2].w[jp]   = cvtpk(rh[0], rh[1]);
      }
    }
#pragma unroll
    for (int dc = 0; dc < 4; ++dc) qf[dc] = U[dc].v;
  };
  ropeQ(0, qfA);
  ropeQ(16, qfB);

  const unsigned short* Kbase = Kb + (size_t)b*SEQ*128;
  const unsigned short* Vbase = Vt + (size_t)b*128*SEQ;

  const int krow = tid >> 4;                          // 0..15
  const int kchunk = (tid & 15) ^ (krow & 7);         // inverse swizzle on source
  const int vrow = tid >> 3;                          // 0..31
  const int vchunk = (tid & 7) ^ (vrow & 7);          // inverse swizzle on source

  auto stage = [&](int buf, int tile){                // 8 gload_lds per thread
    const int n0 = tile * 64;
#pragma unroll
    for (int ck = 0; ck < 4; ++ck){                   // K: 64 rows x 128B
      const unsigned short* gp = Kbase + (size_t)(n0 + ck*16 + krow)*128 + kchunk*8;
      unsigned short* lp = &kls[buf][(ck*256 + tid) * 8];
      __builtin_amdgcn_global_load_lds((const __attribute__((address_space(1))) void*)gp,
                                       (__attribute__((address_space(3))) void*)lp, 16, 0, 0);
    }
#pragma unroll
    for (int cv = 0; cv < 4; ++cv){                   // V: 128 d-rows x 64 keys
      const unsigned short* gp = Vbase + (size_t)(cv*32 + vrow)*SEQ + n0 + vchunk*8;
      unsigned short* lp = &vls[buf][(cv*256 + tid) * 8];
      __builtin_amdgcn_global_load_lds((const __attribute__((address_space(1))) void*)gp,
                                       (__attribute__((address_space(3))) void*)lp, 16, 0, 0);
    }
  };

  f32x4 oA[8] = {}, oB[8] = {};
  float sA = 0.f, sB = 0.f;              // lane-local partial softmax sums
  const int ksw = (m & 7);
  const int vsw = (m & 7);

  auto process = [&](f32x4 a0, f32x4 a1, f32x4 c0, f32x4 c1, const bf16x8* vf){
    float pA0[4], pA1[4], pB0[4], pB1[4];
#pragma unroll
    for (int r = 0; r < 4; ++r){
      pA0[r] = EXP2(fminf(a0[r], 100.f)); sA += pA0[r];
      pA1[r] = EXP2(fminf(a1[r], 100.f)); sA += pA1[r];
      pB0[r] = EXP2(fminf(c0[r], 100.f)); sB += pB0[r];
      pB1[r] = EXP2(fminf(c1[r], 100.f)); sB += pB1[r];
    }
    unsigned int A01 = cvtpk(pA0[0], pA0[1]), A23 = cvtpk(pA0[2], pA0[3]);
    unsigned int A45 = cvtpk(pA1[0], pA1[1]), A67 = cvtpk(pA1[2], pA1[3]);
    u32x2 tA0 = __builtin_amdgcn_permlane32_swap(A01, A45, false, false);
    u32x2 wA02 = __builtin_amdgcn_permlane16_swap(tA0[0], tA0[1], false, false);
    u32x2 tA1 = __builtin_amdgcn_permlane32_swap(A23, A67, false, false);
    u32x2 wA13 = __builtin_amdgcn_permlane16_swap(tA1[0], tA1[1], false, false);
    union { unsigned int w[4]; bf16x8 v; } UA;
    UA.w[0] = wA02[0]; UA.w[1] = wA13[0]; UA.w[2] = wA02[1]; UA.w[3] = wA13[1];
    unsigned int B01 = cvtpk(pB0[0], pB0[1]), B23 = cvtpk(pB0[2], pB0[3]);
    unsigned int B45 = cvtpk(pB1[0], pB1[1]), B67 = cvtpk(pB1[2], pB1[3]);
    u32x2 tB0 = __builtin_amdgcn_permlane32_swap(B01, B45, false, false);
    u32x2 wB02 = __builtin_amdgcn_permlane16_swap(tB0[0], tB0[1], false, false);
    u32x2 tB1 = __builtin_amdgcn_permlane32_swap(B23, B67, false, false);
    u32x2 wB13 = __builtin_amdgcn_permlane16_swap(tB1[0], tB1[1], false, false);
    union { unsigned int w[4]; bf16x8 v; } UB;
    UB.w[0] = wB02[0]; UB.w[1] = wB13[0]; UB.w[2] = wB02[1]; UB.w[3] = wB13[1];
    __builtin_amdgcn_s_setprio(1);
#pragma unroll
    for (int dt = 0; dt < 8; ++dt){
      oA[dt] = __builtin_amdgcn_mfma_f32_16x16x32_bf16(UA.v, vf[dt], oA[dt], 0, 0, 0);
      oB[dt] = __builtin_amdgcn_mfma_f32_16x16x32_bf16(UB.v, vf[dt], oB[dt], 0, 0, 0);
    }
    __builtin_amdgcn_s_setprio(0);
  };

  stage(0, 0);
  stage(1, 1);                           // 16 loads/wave in flight
  const int NT = SEQ / 64;               // 32 tiles
  for (int t = 0; t < NT; ++t){
    const int cur = t & 1;
    if (t + 1 < NT) asm volatile("s_waitcnt vmcnt(8)" ::: "memory");
    else            asm volatile("s_waitcnt vmcnt(0)" ::: "memory");
    __builtin_amdgcn_s_barrier();        // tile t resident in buf[cur]

    const unsigned short* kb = kls[cur];
    const unsigned short* vb = vls[cur];

    // ===== pass 0: keys 0..31 of tile =====
    bf16x8 kf[8], vf[8];
#pragma unroll
    for (int dc = 0; dc < 4; ++dc){
      kf[dc]     = *(const bf16x8*)&kb[(size_t)m*128 + ((dc*4 + g) ^ ksw)*8];
      kf[4 + dc] = *(const bf16x8*)&kb[(size_t)(16 + m)*128 + ((dc*4 + g) ^ ksw)*8];
    }
    f32x4 a0 = {0,0,0,0}, a1 = {0,0,0,0}, c0 = {0,0,0,0}, c1 = {0,0,0,0};
    __builtin_amdgcn_s_setprio(1);
#pragma unroll
    for (int dc = 0; dc < 4; ++dc){
      a0 = __builtin_amdgcn_mfma_f32_16x16x32_bf16(kf[dc], qfA[dc], a0, 0, 0, 0);
      c0 = __builtin_amdgcn_mfma_f32_16x16x32_bf16(kf[dc], qfB[dc], c0, 0, 0, 0);
    }
#pragma unroll
    for (int dc = 0; dc < 4; ++dc){
      a1 = __builtin_amdgcn_mfma_f32_16x16x32_bf16(kf[4 + dc], qfA[dc], a1, 0, 0, 0);
      c1 = __builtin_amdgcn_mfma_f32_16x16x32_bf16(kf[4 + dc], qfB[dc], c1, 0, 0, 0);
    }
    __builtin_amdgcn_s_setprio(0);
#pragma unroll
    for (int dt = 0; dt < 8; ++dt)
      vf[dt] = *(const bf16x8*)&vb[(size_t)(dt*16 + m)*64 + ((g ^ vsw))*8];
    process(a0, a1, c0, c1, vf);

    // ===== pass 1: keys 32..63 of tile =====
#pragma unroll
    for (int dc = 0; dc < 4; ++dc){
      kf[dc]     = *(const bf16x8*)&kb[(size_t)(32 + m)*128 + ((dc*4 + g) ^ ksw)*8];
      kf[4 + dc] = *(const bf16x8*)&kb[(size_t)(48 + m)*128 + ((dc*4 + g) ^ ksw)*8];
    }
    f32x4 a2 = {0,0,0,0}, a3 = {0,0,0,0}, c2 = {0,0,0,0}, c3 = {0,0,0,0};
    __builtin_amdgcn_s_setprio(1);
#pragma unroll
    for (int dc = 0; dc < 4; ++dc){
      a2 = __builtin_amdgcn_mfma_f32_16x16x32_bf16(kf[dc], qfA[dc], a2, 0, 0, 0);
      c2 = __builtin_amdgcn_mfma_f32_16x16x32_bf16(kf[dc], qfB[dc], c2, 0, 0, 0);
    }
#pragma unroll
    for (int dc = 0; dc < 4; ++dc){
      a3 = __builtin_amdgcn_mfma_f32_16x16x32_bf16(kf[4 + dc], qfA[dc], a3, 0, 0, 0);
      c3 = __builtin_amdgcn_mfma_f32_16x16x32_bf16(kf[4 + dc], qfB[dc], c3, 0, 0, 0);
    }
    __builtin_amdgcn_s_setprio(0);
#pragma unroll
    for (int dt = 0; dt < 8; ++dt)
      vf[dt] = *(const bf16x8*)&vb[(size_t)(dt*16 + m)*64 + (((4 + g) ^ vsw))*8];

    asm volatile("s_waitcnt lgkmcnt(0)" ::: "memory");
    __builtin_amdgcn_s_barrier();
    if (t + 2 < NT) stage(cur, t + 2);

    process(a2, a3, c2, c3, vf);         // register-only; overlaps staging
  }

  // total sum per query (across 4 g-lanes), then normalize + write
  sA += __shfl_xor(sA, 16); sA += __shfl_xor(sA, 32);
  sB += __shfl_xor(sB, 16); sB += __shfl_xor(sB, 32);
  float invA = 1.f / sA, invB = 1.f / sB;
  float ivA[4], ivB[4];
#pragma unroll
  for (int r = 0; r < 4; ++r){
    ivA[r] = __shfl(invA, g*4 + r);
    ivB[r] = __shfl(invB, g*4 + r);
  }
  unsigned short* orowA = Ob + (size_t)((b << 11) + q0)*HID + h*128;
  unsigned short* orowB = orowA + (size_t)16*HID;
#pragma unroll
  for (int dt = 0; dt < 8; ++dt)
#pragma unroll
    for (int r = 0; r < 4; ++r){
      orowA[(size_t)(g*4 + r)*HID + dt*16 + m] = f2bf(oA[dt][r] * ivA[r]);
      orowB[(size_t)(g*4 + r)*HID + dt*16 + m] = f2bf(oB[dt][r] * ivB[r]);
    }
}

// ---------------------------------------------------------------- launch
extern "C" void kernel_launch(void* const* d_in, const int* in_sizes, int n_in,
                              void* d_out, int out_size, void* d_ws, size_t ws_size,
                              hipStream_t stream){
  const float* hidden = (const float*)d_in[0];
  const float* cosb   = (const float*)d_in[1];
  const float* sinb   = (const float*)d_in[2];
  const float* wqkv   = (const float*)d_in[3];
  const float* wo     = (const float*)d_in[4];
  float* out = (float*)d_out;                    // f32 output

  char* ws = (char*)d_ws;
  unsigned short* qkvb  = (unsigned short*)ws; ws += (size_t)BATCH*SEQ*NQKV*2;  // 18.9 MB
  unsigned short* hidb  = (unsigned short*)ws; ws += (size_t)BATCH*SEQ*HID*2;   // 16.8 MB
  unsigned short* attnb = hidb;                                                 // alias: dead after gemm1
  unsigned short* Kbf   = (unsigned short*)ws; ws += (size_t)BATCH*SEQ*128*2;   // 1.05 MB
  unsigned short* Vt    = (unsigned short*)ws; ws += (size_t)BATCH*SEQ*128*2;   // 1.05 MB
  unsigned short* wqkvT = (unsigned short*)ws; ws += (size_t)NQKV*HID*2;        // 9.44 MB
  unsigned short* woT   = wqkvT;                                                // alias: dead after gemm1

  convert_bf16<<<dim3(BATCH*SEQ*HID/4096), 256, 0, stream>>>(hidden, hidb);
  transpose_f2b<<<dim3(NQKV/64, HID/64), 256, 0, stream>>>(wqkv, wqkvT, HID, NQKV);
  gemm_bt<false><<<dim3(BATCH*SEQ/128, NQKV/128), 256, 0, stream>>>(hidb, wqkvT, qkvb,
                                                                    BATCH*SEQ, NQKV, HID);
  rope_kv<<<dim3(BATCH*SEQ), 128, 0, stream>>>(qkvb, cosb, sinb, Kbf, Vt);
  transpose_f2b<<<dim3(HID/64, HID/64), 256, 0, stream>>>(wo, woT, HID, HID);
  attn_fwd<<<dim3(SEQ/128 * BATCH*H_Q), 256, 0, stream>>>(qkvb, cosb, sinb, Kbf, Vt, attnb);
  gemm_bt<true><<<dim3(BATCH*SEQ/128, HID/128), 256, 0, stream>>>(attnb, woT, out,
                                                                  BATCH*SEQ, HID, HID);
}

// Round 20
// 197.598 us; speedup vs baseline: 1.0154x; 1.0154x over previous
//
#include <hip/hip_runtime.h>

typedef __attribute__((ext_vector_type(8))) short bf16x8;
typedef __attribute__((ext_vector_type(4))) float f32x4;
typedef __attribute__((ext_vector_type(8))) unsigned short u16x8;
typedef __attribute__((ext_vector_type(2))) unsigned int u32x2;

#define H_Q   16
#define NH    18            // 16 q heads + 1 k + 1 v
#define SEQ   2048
#define BATCH 2
#define HID   2048
#define NQKV  2304          // NH*128
// q pre-scale: (1/sqrt(128)) * log2(e)  -> scores arrive in log2 domain
#define QK_SCALE2 0.1275174313f

// native v_exp_f32 (exact in clamped domain); fallback keeps correctness
#if defined(__has_builtin)
# if __has_builtin(__builtin_amdgcn_exp2f)
#  define EXP2(x) __builtin_amdgcn_exp2f(x)
# endif
#endif
#ifndef EXP2
# define EXP2(x) exp2f(x)
#endif

__device__ __forceinline__ float bf2f(unsigned short u){
  union { unsigned int u; float f; } x; x.u = ((unsigned int)u) << 16; return x.f;
}
__device__ __forceinline__ unsigned short f2bf(float f){
  union { float f; unsigned int u; } x; x.f = f;
  unsigned int r = x.u + 0x7fffu + ((x.u >> 16) & 1u);
  return (unsigned short)(r >> 16);
}
// packed f32x2 -> bf16x2 (RNE, matches f2bf) in ONE VALU instruction
__device__ __forceinline__ unsigned int cvtpk(float lo, float hi){
  unsigned int r;
  asm("v_cvt_pk_bf16_f32 %0, %1, %2" : "=v"(r) : "v"(lo), "v"(hi));
  return r;
}

// ---------------------------------------------------------------- f32 -> bf16 convert
__global__ __launch_bounds__(256) void convert_bf16(const float* __restrict__ src,
                                                    unsigned short* __restrict__ dst){
  const size_t i0 = ((size_t)blockIdx.x * 256 + threadIdx.x) * 16;
  f32x4 a = *(const f32x4*)(src + i0);
  f32x4 b = *(const f32x4*)(src + i0 + 4);
  f32x4 c = *(const f32x4*)(src + i0 + 8);
  f32x4 d = *(const f32x4*)(src + i0 + 12);
  u16x8 lo, hi;
#pragma unroll
  for (int j = 0; j < 4; ++j){
    lo[j] = f2bf(a[j]); lo[4+j] = f2bf(b[j]);
    hi[j] = f2bf(c[j]); hi[4+j] = f2bf(d[j]);
  }
  *(u16x8*)(dst + i0)     = lo;
  *(u16x8*)(dst + i0 + 8) = hi;
}

// ---------------------------------------------------------------- transpose + convert
__global__ __launch_bounds__(256) void transpose_f2b(const float* __restrict__ W,
                                                     unsigned short* __restrict__ WT,
                                                     int K, int N){
  __shared__ float tile[64][72];
  const int t = threadIdx.x;
  const int nt = blockIdx.x * 64, kt = blockIdx.y * 64;
#pragma unroll
  for (int p = 0; p < 2; ++p){
    int slot = p*256 + t, r = slot >> 3, c = (slot & 7) * 8;
    *(f32x4*)&tile[r][c]     = *(const f32x4*)(W + (size_t)(kt + r)*N + nt + c);
    *(f32x4*)&tile[r][c + 4] = *(const f32x4*)(W + (size_t)(kt + r)*N + nt + c + 4);
  }
  __syncthreads();
#pragma unroll
  for (int p = 0; p < 2; ++p){
    int slot = p*256 + t, r = slot >> 3, c = (slot & 7) * 8;
    u16x8 v;
#pragma unroll
    for (int j = 0; j < 8; ++j) v[j] = f2bf(tile[c + j][r]);
    *(u16x8*)(WT + (size_t)(nt + r)*K + kt + c) = v;
  }
}

// ---------------------------------------------------------------- GEMM (B^T input)
template<bool F32OUT>
__global__ __launch_bounds__(256, 2) void gemm_bt(const unsigned short* __restrict__ A,
                                                  const unsigned short* __restrict__ Bt,
                                                  void* __restrict__ Cv,
                                                  int M, int N, int K){
  __shared__ unsigned short lds[2][2][128*32];
  const int tid  = threadIdx.x;
  const int wave = tid >> 6, lane = tid & 63;
  const int row0 = blockIdx.x * 128, col0 = blockIdx.y * 128;
  const int wr = (wave >> 1) * 64, wc = (wave & 1) * 64;
  const int lm = lane & 15, lk = (lane >> 4) * 8;
  f32x4 acc[4][4] = {};

  auto stage = [&](int buf, int kt){
#pragma unroll
    for (int i = 0; i < 2; ++i){
      int slot = i*256 + tid;
      int r = slot >> 2, kc = (slot & 3) * 8;
      const unsigned short* ga = A  + (size_t)(row0 + r)*K + kt*32 + kc;
      const unsigned short* gb = Bt + (size_t)(col0 + r)*K + kt*32 + kc;
      unsigned short* la = &lds[buf][0][(i*256 + (wave << 6)) * 8];
      unsigned short* lb = &lds[buf][1][(i*256 + (wave << 6)) * 8];
      __builtin_amdgcn_global_load_lds((const __attribute__((address_space(1))) void*)ga,
                                       (__attribute__((address_space(3))) void*)la, 16, 0, 0);
      __builtin_amdgcn_global_load_lds((const __attribute__((address_space(1))) void*)gb,
                                       (__attribute__((address_space(3))) void*)lb, 16, 0, 0);
    }
  };

  stage(0, 0);
  const int KT = K >> 5;
  int buf = 0;
  for (int kt = 0; kt < KT; ++kt){
    __syncthreads();
    if (kt + 1 < KT) stage(buf ^ 1, kt + 1);
    const unsigned short* la = lds[buf][0];
    const unsigned short* lb = lds[buf][1];
    bf16x8 af[4], bfr[4];
#pragma unroll
    for (int i = 0; i < 4; ++i) af[i]  = *(const bf16x8*)&la[(wr + i*16 + lm)*32 + lk];
#pragma unroll
    for (int j = 0; j < 4; ++j) bfr[j] = *(const bf16x8*)&lb[(wc + j*16 + lm)*32 + lk];
#pragma unroll
    for (int i = 0; i < 4; ++i)
#pragma unroll
      for (int j = 0; j < 4; ++j)
        acc[i][j] = __builtin_amdgcn_mfma_f32_16x16x32_bf16(af[i], bfr[j], acc[i][j], 0, 0, 0);
    buf ^= 1;
  }

#pragma unroll
  for (int i = 0; i < 4; ++i){
    int row = row0 + wr + i*16 + (lane >> 4) * 4;
#pragma unroll
    for (int j = 0; j < 4; ++j){
      int col = col0 + wc + j*16 + lm;
#pragma unroll
      for (int r = 0; r < 4; ++r){
        if (F32OUT) ((float*)Cv)[(size_t)(row + r)*N + col] = acc[i][j][r];
        else ((unsigned short*)Cv)[(size_t)(row + r)*N + col] = f2bf(acc[i][j][r]);
      }
    }
  }
}

// ---------------------------------------------------------------- RoPE + pack K + transpose V
__global__ __launch_bounds__(256) void rope_pack(unsigned short* __restrict__ qkv,
                                                 const float* __restrict__ cosb,
                                                 const float* __restrict__ sinb,
                                                 unsigned short* __restrict__ Kb,
                                                 unsigned short* __restrict__ Vt){
  const int bs = blockIdx.x;
  const int s = bs & (SEQ-1), b = bs >> 11;
  const int t = threadIdx.x;
  unsigned short* row = qkv + (size_t)bs * NQKV;
  const float* cr = cosb + (size_t)s * 128;
  const float* sr = sinb + (size_t)s * 128;
  const int h = t >> 4, d0 = (t & 15) * 4;
  unsigned short* q = row + h * 128;
#pragma unroll
  for (int i = 0; i < 4; ++i){
    int d = d0 + i;
    float c  = cr[d], sn = sr[d];
    float x1 = bf2f(q[d]),  x2 = bf2f(q[d + 64]);
    q[d]      = f2bf((x1*c - x2*sn) * QK_SCALE2);
    q[d + 64] = f2bf((x2*c + x1*sn) * QK_SCALE2);
  }
  if (t < 64){
    const unsigned short* kk = row + H_Q*128;
    int d = t;
    float c  = cr[d], sn = sr[d];
    float x1 = bf2f(kk[d]), x2 = bf2f(kk[d + 64]);
    unsigned short* ko = Kb + ((size_t)b*SEQ + s)*128;
    ko[d]      = f2bf(x1*c - x2*sn);
    ko[d + 64] = f2bf(x2*c + x1*sn);
  }
  if (t < 128){
    Vt[((size_t)b*128 + t)*SEQ + s] = row[(H_Q + 1)*128 + t];
  }
}

// ---------------------------------------------------------------- attention
// 64-key LDS tiles (2 x 32-key passes per tile): halves barrier/loop overhead.
// Counted-vmcnt prefetch (2 tiles ahead), native exp2, cvt_pk+permlane P path.
__global__ __launch_bounds__(256, 2) void attn_fwd(const unsigned short* __restrict__ qkv,
                                                   const unsigned short* __restrict__ Kb,
                                                   const unsigned short* __restrict__ Vt,
                                                   unsigned short* __restrict__ Ob){
  __shared__ unsigned short kls[2][64*128];   // [key][d] swizzled chunk16 ^= key&7 (16KB)
  __shared__ unsigned short vls[2][128*64];   // [d][key] swizzled chunk8 ^= d&7 (16KB)
  const int tid = threadIdx.x, lane = tid & 63;
  const int g = lane >> 4, m = lane & 15;
  const int wg = blockIdx.x;                  // 512 blocks, bh-major
  const int bh = wg >> 4, qb = wg & 15;
  const int b = bh >> 4, h = bh & 15;
  const int q0 = qb * 128 + (tid >> 6) * 32;

  const unsigned short* qrowA = qkv + ((size_t)((b << 11) + q0 + m)*NH + h)*128;
  const unsigned short* qrowB = qrowA + (size_t)16*NH*128;
  bf16x8 qfA[4], qfB[4];
#pragma unroll
  for (int dc = 0; dc < 4; ++dc){
    qfA[dc] = *(const bf16x8*)(qrowA + dc*32 + g*8);
    qfB[dc] = *(const bf16x8*)(qrowB + dc*32 + g*8);
  }

  const unsigned short* Kbase = Kb + (size_t)b*SEQ*128;
  const unsigned short* Vbase = Vt + (size_t)b*128*SEQ;

  const int krow = tid >> 4;                          // 0..15 (K staging row within round)
  const int kchunk = (tid & 15) ^ (krow & 7);         // inverse swizzle on source
  const int vrow = tid >> 3;                          // 0..31 (V staging row within round)
  const int vchunk = (tid & 7) ^ (vrow & 7);          // inverse swizzle on source

  auto stage = [&](int buf, int tile){                // 8 gload_lds per thread
    const int n0 = tile * 64;
#pragma unroll
    for (int ck = 0; ck < 4; ++ck){                   // K: 64 rows x 128B
      const unsigned short* gp = Kbase + (size_t)(n0 + ck*16 + krow)*128 + kchunk*8;
      unsigned short* lp = &kls[buf][(ck*256 + tid) * 8];
      __builtin_amdgcn_global_load_lds((const __attribute__((address_space(1))) void*)gp,
                                       (__attribute__((address_space(3))) void*)lp, 16, 0, 0);
    }
#pragma unroll
    for (int cv = 0; cv < 4; ++cv){                   // V: 128 rows x 128B (64 keys)
      const unsigned short* gp = Vbase + (size_t)(cv*32 + vrow)*SEQ + n0 + vchunk*8;
      unsigned short* lp = &vls[buf][(cv*256 + tid) * 8];
      __builtin_amdgcn_global_load_lds((const __attribute__((address_space(1))) void*)gp,
                                       (__attribute__((address_space(3))) void*)lp, 16, 0, 0);
    }
  };

  f32x4 oA[8] = {}, oB[8] = {};
  float sA = 0.f, sB = 0.f;              // lane-local partial sums
  const int ksw = (m & 7);
  const int vsw = (m & 7);

  // register-only softmax+pack+PV for one 32-key group
  auto process = [&](f32x4 a0, f32x4 a1, f32x4 c0, f32x4 c1, const bf16x8* vf){
    float pA0[4], pA1[4], pB0[4], pB1[4];
#pragma unroll
    for (int r = 0; r < 4; ++r){
      pA0[r] = EXP2(fminf(a0[r], 100.f)); sA += pA0[r];
      pA1[r] = EXP2(fminf(a1[r], 100.f)); sA += pA1[r];
      pB0[r] = EXP2(fminf(c0[r], 100.f)); sB += pB0[r];
      pB1[r] = EXP2(fminf(c1[r], 100.f)); sB += pB1[r];
    }
    unsigned int A01 = cvtpk(pA0[0], pA0[1]), A23 = cvtpk(pA0[2], pA0[3]);
    unsigned int A45 = cvtpk(pA1[0], pA1[1]), A67 = cvtpk(pA1[2], pA1[3]);
    u32x2 tA0 = __builtin_amdgcn_permlane32_swap(A01, A45, false, false);
    u32x2 wA02 = __builtin_amdgcn_permlane16_swap(tA0[0], tA0[1], false, false);
    u32x2 tA1 = __builtin_amdgcn_permlane32_swap(A23, A67, false, false);
    u32x2 wA13 = __builtin_amdgcn_permlane16_swap(tA1[0], tA1[1], false, false);
    union { unsigned int w[4]; bf16x8 v; } UA;
    UA.w[0] = wA02[0]; UA.w[1] = wA13[0]; UA.w[2] = wA02[1]; UA.w[3] = wA13[1];
    unsigned int B01 = cvtpk(pB0[0], pB0[1]), B23 = cvtpk(pB0[2], pB0[3]);
    unsigned int B45 = cvtpk(pB1[0], pB1[1]), B67 = cvtpk(pB1[2], pB1[3]);
    u32x2 tB0 = __builtin_amdgcn_permlane32_swap(B01, B45, false, false);
    u32x2 wB02 = __builtin_amdgcn_permlane16_swap(tB0[0], tB0[1], false, false);
    u32x2 tB1 = __builtin_amdgcn_permlane32_swap(B23, B67, false, false);
    u32x2 wB13 = __builtin_amdgcn_permlane16_swap(tB1[0], tB1[1], false, false);
    union { unsigned int w[4]; bf16x8 v; } UB;
    UB.w[0] = wB02[0]; UB.w[1] = wB13[0]; UB.w[2] = wB02[1]; UB.w[3] = wB13[1];
    __builtin_amdgcn_s_setprio(1);
#pragma unroll
    for (int dt = 0; dt < 8; ++dt){
      oA[dt] = __builtin_amdgcn_mfma_f32_16x16x32_bf16(UA.v, vf[dt], oA[dt], 0, 0, 0);
      oB[dt] = __builtin_amdgcn_mfma_f32_16x16x32_bf16(UB.v, vf[dt], oB[dt], 0, 0, 0);
    }
    __builtin_amdgcn_s_setprio(0);
  };

  stage(0, 0);
  stage(1, 1);                           // 16 loads/wave in flight
  const int NT = SEQ / 64;               // 32 tiles
  for (int t = 0; t < NT; ++t){
    const int cur = t & 1;
    if (t + 1 < NT) asm volatile("s_waitcnt vmcnt(8)" ::: "memory");
    else            asm volatile("s_waitcnt vmcnt(0)" ::: "memory");
    __builtin_amdgcn_s_barrier();        // tile t resident in buf[cur]

    const unsigned short* kb = kls[cur];
    const unsigned short* vb = vls[cur];

    // ===== pass 0: keys 0..31 of tile =====
    bf16x8 kf[8], vf[8];
#pragma unroll
    for (int dc = 0; dc < 4; ++dc){
      kf[dc]     = *(const bf16x8*)&kb[(size_t)m*128 + ((dc*4 + g) ^ ksw)*8];
      kf[4 + dc] = *(const bf16x8*)&kb[(size_t)(16 + m)*128 + ((dc*4 + g) ^ ksw)*8];
    }
    f32x4 a0 = {0,0,0,0}, a1 = {0,0,0,0}, c0 = {0,0,0,0}, c1 = {0,0,0,0};
    __builtin_amdgcn_s_setprio(1);
#pragma unroll
    for (int dc = 0; dc < 4; ++dc){
      a0 = __builtin_amdgcn_mfma_f32_16x16x32_bf16(kf[dc], qfA[dc], a0, 0, 0, 0);
      c0 = __builtin_amdgcn_mfma_f32_16x16x32_bf16(kf[dc], qfB[dc], c0, 0, 0, 0);
    }
#pragma unroll
    for (int dc = 0; dc < 4; ++dc){
      a1 = __builtin_amdgcn_mfma_f32_16x16x32_bf16(kf[4 + dc], qfA[dc], a1, 0, 0, 0);
      c1 = __builtin_amdgcn_mfma_f32_16x16x32_bf16(kf[4 + dc], qfB[dc], c1, 0, 0, 0);
    }
    __builtin_amdgcn_s_setprio(0);
#pragma unroll
    for (int dt = 0; dt < 8; ++dt)
      vf[dt] = *(const bf16x8*)&vb[(size_t)(dt*16 + m)*64 + ((g ^ vsw))*8];
    process(a0, a1, c0, c1, vf);

    // ===== pass 1: keys 32..63 of tile =====
#pragma unroll
    for (int dc = 0; dc < 4; ++dc){
      kf[dc]     = *(const bf16x8*)&kb[(size_t)(32 + m)*128 + ((dc*4 + g) ^ ksw)*8];
      kf[4 + dc] = *(const bf16x8*)&kb[(size_t)(48 + m)*128 + ((dc*4 + g) ^ ksw)*8];
    }
    f32x4 a2 = {0,0,0,0}, a3 = {0,0,0,0}, c2 = {0,0,0,0}, c3 = {0,0,0,0};
    __builtin_amdgcn_s_setprio(1);
#pragma unroll
    for (int dc = 0; dc < 4; ++dc){
      a2 = __builtin_amdgcn_mfma_f32_16x16x32_bf16(kf[dc], qfA[dc], a2, 0, 0, 0);
      c2 = __builtin_amdgcn_mfma_f32_16x16x32_bf16(kf[dc], qfB[dc], c2, 0, 0, 0);
    }
#pragma unroll
    for (int dc = 0; dc < 4; ++dc){
      a3 = __builtin_amdgcn_mfma_f32_16x16x32_bf16(kf[4 + dc], qfA[dc], a3, 0, 0, 0);
      c3 = __builtin_amdgcn_mfma_f32_16x16x32_bf16(kf[4 + dc], qfB[dc], c3, 0, 0, 0);
    }
    __builtin_amdgcn_s_setprio(0);
#pragma unroll
    for (int dt = 0; dt < 8; ++dt)
      vf[dt] = *(const bf16x8*)&vb[(size_t)(dt*16 + m)*64 + (((4 + g) ^ vsw))*8];

    // all LDS reads of this tile are in flight to registers; after the barrier
    // buf[cur] may be overwritten by tile t+2's stage
    asm volatile("s_waitcnt lgkmcnt(0)" ::: "memory");
    __builtin_amdgcn_s_barrier();
    if (t + 2 < NT) stage(cur, t + 2);

    process(a2, a3, c2, c3, vf);         // register-only; overlaps staging
  }

  // total sum per query (across 4 g-lanes), then normalize + write
  sA += __shfl_xor(sA, 16); sA += __shfl_xor(sA, 32);
  sB += __shfl_xor(sB, 16); sB += __shfl_xor(sB, 32);
  float invA = 1.f / sA, invB = 1.f / sB;
  float ivA[4], ivB[4];
#pragma unroll
  for (int r = 0; r < 4; ++r){
    ivA[r] = __shfl(invA, g*4 + r);
    ivB[r] = __shfl(invB, g*4 + r);
  }
  unsigned short* orowA = Ob + (size_t)((b << 11) + q0)*HID + h*128;
  unsigned short* orowB = orowA + (size_t)16*HID;
#pragma unroll
  for (int dt = 0; dt < 8; ++dt)
#pragma unroll
    for (int r = 0; r < 4; ++r){
      orowA[(size_t)(g*4 + r)*HID + dt*16 + m] = f2bf(oA[dt][r] * ivA[r]);
      orowB[(size_t)(g*4 + r)*HID + dt*16 + m] = f2bf(oB[dt][r] * ivB[r]);
    }
}

// ---------------------------------------------------------------- launch
extern "C" void kernel_launch(void* const* d_in, const int* in_sizes, int n_in,
                              void* d_out, int out_size, void* d_ws, size_t ws_size,
                              hipStream_t stream){
  const float* hidden = (const float*)d_in[0];
  const float* cosb   = (const float*)d_in[1];
  const float* sinb   = (const float*)d_in[2];
  const float* wqkv   = (const float*)d_in[3];
  const float* wo     = (const float*)d_in[4];
  float* out = (float*)d_out;                    // f32 output

  char* ws = (char*)d_ws;
  unsigned short* qkvb  = (unsigned short*)ws; ws += (size_t)BATCH*SEQ*NQKV*2;  // 18.9 MB
  unsigned short* hidb  = (unsigned short*)ws; ws += (size_t)BATCH*SEQ*HID*2;   // 16.8 MB
  unsigned short* attnb = hidb;                                                 // alias: dead after gemm1
  unsigned short* Kbf   = (unsigned short*)ws; ws += (size_t)BATCH*SEQ*128*2;   // 1.05 MB
  unsigned short* Vt    = (unsigned short*)ws; ws += (size_t)BATCH*SEQ*128*2;   // 1.05 MB
  unsigned short* wqkvT = (unsigned short*)ws; ws += (size_t)NQKV*HID*2;        // 9.44 MB
  unsigned short* woT   = wqkvT;                                                // alias: dead after gemm1

  convert_bf16<<<dim3(BATCH*SEQ*HID/4096), 256, 0, stream>>>(hidden, hidb);
  transpose_f2b<<<dim3(NQKV/64, HID/64), 256, 0, stream>>>(wqkv, wqkvT, HID, NQKV);
  gemm_bt<false><<<dim3(BATCH*SEQ/128, NQKV/128), 256, 0, stream>>>(hidb, wqkvT, qkvb,
                                                                    BATCH*SEQ, NQKV, HID);
  rope_pack<<<dim3(BATCH*SEQ), 256, 0, stream>>>(qkvb, cosb, sinb, Kbf, Vt);
  transpose_f2b<<<dim3(HID/64, HID/64), 256, 0, stream>>>(wo, woT, HID, HID);
  attn_fwd<<<dim3(SEQ/128 * BATCH*H_Q), 256, 0, stream>>>(qkvb, Kbf, Vt, attnb);
  gemm_bt<true><<<dim3(BATCH*SEQ/128, HID/128), 256, 0, stream>>>(attnb, woT, out,
                                                                  BATCH*SEQ, HID, HID);
}